// Round 1
// baseline (149.507 us; speedup 1.0000x reference)
//
#include <hip/hip_runtime.h>

// Mamba selective scan: y[b,t,e] = sum_n h[b,t,e,n]*C[b,t,n] + D[e]*x[b,t,e]
//   h_t = exp(delta_t * A) * h_{t-1} + delta_t * B_t * x_t
// 3-pass chunked scan: (1) per-chunk local scan -> Q, sum(delta) -> Dsum
//                      (2) serial scan over chunk summaries -> Hprev
//                      (3) re-scan each chunk seeded with Hprev, fused y epilogue.
// Lane <-> ed mapping: x/delta/y accesses perfectly coalesced; all N=16 states
// live in registers per lane (no cross-lane reduce). exp(delta*A) computed as
// exp2((A*log2e)*delta) -> single v_exp_f32.

#define LOG2E 1.4426950408889634f

constexpr int BATCH = 2;
constexpr int SEQ   = 2048;
constexpr int ED    = 1024;
constexpr int NS    = 16;

constexpr int NC  = 64;         // number of chunks
constexpr int CT  = SEQ / NC;   // timesteps per chunk = 32
constexpr int EDG = 256;        // ed channels per block
constexpr int NEG = ED / EDG;   // ed groups = 4

// ---------------- pass 1: chunk-local scan ----------------
__global__ __launch_bounds__(EDG) void ssm_pass1(
    const float* __restrict__ x, const float* __restrict__ dl,
    const float* __restrict__ A, const float* __restrict__ B,
    float* __restrict__ Q, float* __restrict__ Dsum)
{
    const int c = blockIdx.x, g = blockIdx.y, b = blockIdx.z;
    const int tid = threadIdx.x;
    const int ed = g * EDG + tid;

    __shared__ alignas(16) float Bs[CT * NS];   // 2 KB
    const long tbase = (long)b * SEQ + (long)c * CT;
    for (int i = tid; i < CT * NS; i += EDG) Bs[i] = B[tbase * NS + i];
    __syncthreads();

    float A2[NS];
    {
        const float4* Ap = reinterpret_cast<const float4*>(A + (long)ed * NS);
        #pragma unroll
        for (int k = 0; k < 4; ++k) {
            float4 a4 = Ap[k];
            A2[4*k+0] = a4.x * LOG2E; A2[4*k+1] = a4.y * LOG2E;
            A2[4*k+2] = a4.z * LOG2E; A2[4*k+3] = a4.w * LOG2E;
        }
    }

    float h[NS];
    #pragma unroll
    for (int n = 0; n < NS; ++n) h[n] = 0.f;
    float dsum = 0.f;

    const float* dp = dl + tbase * ED + ed;
    const float* xp = x  + tbase * ED + ed;

    #pragma unroll 4
    for (int t = 0; t < CT; ++t) {
        float dlt = dp[(long)t * ED];
        float xv  = xp[(long)t * ED];
        dsum += dlt;
        float dx = dlt * xv;
        const float4* Bs4 = reinterpret_cast<const float4*>(&Bs[t * NS]);
        #pragma unroll
        for (int k = 0; k < 4; ++k) {
            float4 b4 = Bs4[k];
            h[4*k+0] = fmaf(exp2f(dlt * A2[4*k+0]), h[4*k+0], dx * b4.x);
            h[4*k+1] = fmaf(exp2f(dlt * A2[4*k+1]), h[4*k+1], dx * b4.y);
            h[4*k+2] = fmaf(exp2f(dlt * A2[4*k+2]), h[4*k+2], dx * b4.z);
            h[4*k+3] = fmaf(exp2f(dlt * A2[4*k+3]), h[4*k+3], dx * b4.w);
        }
    }

    const long qo = ((long)(c * BATCH + b) * ED + ed) * NS;
    float4* Qp = reinterpret_cast<float4*>(Q + qo);
    #pragma unroll
    for (int k = 0; k < 4; ++k)
        Qp[k] = make_float4(h[4*k+0], h[4*k+1], h[4*k+2], h[4*k+3]);
    Dsum[(long)(c * BATCH + b) * ED + ed] = dsum;
}

// ---------------- pass 2: inter-chunk scan ----------------
__global__ __launch_bounds__(256) void ssm_pass2(
    const float* __restrict__ A, const float* __restrict__ Q,
    const float* __restrict__ Dsum, float* __restrict__ Hprev)
{
    const int idx = blockIdx.x * 256 + threadIdx.x;   // (b*ED+ed)*NS+n
    const int n  = idx & (NS - 1);
    const int ed = (idx >> 4) & (ED - 1);
    const int b  = idx >> 14;

    const float A2 = A[(long)ed * NS + n] * LOG2E;
    float h = 0.f;
    for (int c = 0; c < NC; ++c) {
        const long o = ((long)(c * BATCH + b) * ED + ed) * NS + n;
        Hprev[o] = h;
        float P = exp2f(A2 * Dsum[(long)(c * BATCH + b) * ED + ed]);
        h = fmaf(P, h, Q[o]);
    }
}

// ---------------- pass 3: re-scan + fused epilogue ----------------
__global__ __launch_bounds__(EDG) void ssm_pass3(
    const float* __restrict__ x, const float* __restrict__ dl,
    const float* __restrict__ A, const float* __restrict__ B,
    const float* __restrict__ C, const float* __restrict__ Dv,
    const float* __restrict__ Hprev, float* __restrict__ y)
{
    const int c = blockIdx.x, g = blockIdx.y, b = blockIdx.z;
    const int tid = threadIdx.x;
    const int ed = g * EDG + tid;

    __shared__ alignas(16) float Bs[CT * NS];
    __shared__ alignas(16) float Cs[CT * NS];
    const long tbase = (long)b * SEQ + (long)c * CT;
    for (int i = tid; i < CT * NS; i += EDG) {
        Bs[i] = B[tbase * NS + i];
        Cs[i] = C[tbase * NS + i];
    }
    __syncthreads();

    float A2[NS];
    {
        const float4* Ap = reinterpret_cast<const float4*>(A + (long)ed * NS);
        #pragma unroll
        for (int k = 0; k < 4; ++k) {
            float4 a4 = Ap[k];
            A2[4*k+0] = a4.x * LOG2E; A2[4*k+1] = a4.y * LOG2E;
            A2[4*k+2] = a4.z * LOG2E; A2[4*k+3] = a4.w * LOG2E;
        }
    }

    float h[NS];
    {
        const long qo = ((long)(c * BATCH + b) * ED + ed) * NS;
        const float4* Hp = reinterpret_cast<const float4*>(Hprev + qo);
        #pragma unroll
        for (int k = 0; k < 4; ++k) {
            float4 h4 = Hp[k];
            h[4*k+0] = h4.x; h[4*k+1] = h4.y; h[4*k+2] = h4.z; h[4*k+3] = h4.w;
        }
    }
    const float dvec = Dv[ed];

    const float* dp = dl + tbase * ED + ed;
    const float* xp = x  + tbase * ED + ed;
    float* yp = y + tbase * ED + ed;

    #pragma unroll 4
    for (int t = 0; t < CT; ++t) {
        float dlt = dp[(long)t * ED];
        float xv  = xp[(long)t * ED];
        float dx = dlt * xv;
        float acc = dvec * xv;
        const float4* Bs4 = reinterpret_cast<const float4*>(&Bs[t * NS]);
        const float4* Cs4 = reinterpret_cast<const float4*>(&Cs[t * NS]);
        #pragma unroll
        for (int k = 0; k < 4; ++k) {
            float4 b4 = Bs4[k];
            float4 c4 = Cs4[k];
            h[4*k+0] = fmaf(exp2f(dlt * A2[4*k+0]), h[4*k+0], dx * b4.x);
            acc = fmaf(h[4*k+0], c4.x, acc);
            h[4*k+1] = fmaf(exp2f(dlt * A2[4*k+1]), h[4*k+1], dx * b4.y);
            acc = fmaf(h[4*k+1], c4.y, acc);
            h[4*k+2] = fmaf(exp2f(dlt * A2[4*k+2]), h[4*k+2], dx * b4.z);
            acc = fmaf(h[4*k+2], c4.z, acc);
            h[4*k+3] = fmaf(exp2f(dlt * A2[4*k+3]), h[4*k+3], dx * b4.w);
            acc = fmaf(h[4*k+3], c4.w, acc);
        }
        yp[(long)t * ED] = acc;
    }
}

// ---------------- fallback (tiny workspace): fully sequential ----------------
__global__ __launch_bounds__(EDG) void ssm_fallback(
    const float* __restrict__ x, const float* __restrict__ dl,
    const float* __restrict__ A, const float* __restrict__ B,
    const float* __restrict__ C, const float* __restrict__ Dv,
    float* __restrict__ y)
{
    const int g = blockIdx.x, b = blockIdx.y;
    const int ed = g * EDG + threadIdx.x;

    float A2[NS];
    {
        const float4* Ap = reinterpret_cast<const float4*>(A + (long)ed * NS);
        #pragma unroll
        for (int k = 0; k < 4; ++k) {
            float4 a4 = Ap[k];
            A2[4*k+0] = a4.x * LOG2E; A2[4*k+1] = a4.y * LOG2E;
            A2[4*k+2] = a4.z * LOG2E; A2[4*k+3] = a4.w * LOG2E;
        }
    }
    float h[NS];
    #pragma unroll
    for (int n = 0; n < NS; ++n) h[n] = 0.f;
    const float dvec = Dv[ed];

    for (int t = 0; t < SEQ; ++t) {
        const long tb = (long)b * SEQ + t;
        float dlt = dl[tb * ED + ed];
        float xv  = x[tb * ED + ed];
        float dx = dlt * xv;
        float acc = dvec * xv;
        const float4* Bp = reinterpret_cast<const float4*>(B + tb * NS);
        const float4* Cp = reinterpret_cast<const float4*>(C + tb * NS);
        #pragma unroll
        for (int k = 0; k < 4; ++k) {
            float4 b4 = Bp[k];
            float4 c4 = Cp[k];
            h[4*k+0] = fmaf(exp2f(dlt * A2[4*k+0]), h[4*k+0], dx * b4.x);
            acc = fmaf(h[4*k+0], c4.x, acc);
            h[4*k+1] = fmaf(exp2f(dlt * A2[4*k+1]), h[4*k+1], dx * b4.y);
            acc = fmaf(h[4*k+1], c4.y, acc);
            h[4*k+2] = fmaf(exp2f(dlt * A2[4*k+2]), h[4*k+2], dx * b4.z);
            acc = fmaf(h[4*k+2], c4.z, acc);
            h[4*k+3] = fmaf(exp2f(dlt * A2[4*k+3]), h[4*k+3], dx * b4.w);
            acc = fmaf(h[4*k+3], c4.w, acc);
        }
        y[tb * ED + ed] = acc;
    }
}

extern "C" void kernel_launch(void* const* d_in, const int* in_sizes, int n_in,
                              void* d_out, int out_size, void* d_ws, size_t ws_size,
                              hipStream_t stream) {
    const float* x  = (const float*)d_in[0];
    const float* dl = (const float*)d_in[1];
    const float* A  = (const float*)d_in[2];
    const float* B  = (const float*)d_in[3];
    const float* C  = (const float*)d_in[4];
    const float* Dv = (const float*)d_in[5];
    float* y = (float*)d_out;

    const size_t qElems = (size_t)NC * BATCH * ED * NS;   // 2M floats
    const size_t dElems = (size_t)NC * BATCH * ED;        // 128K floats
    const size_t need = (2 * qElems + dElems) * sizeof(float);  // ~16.5 MB

    if (ws_size >= need) {
        float* Q     = (float*)d_ws;
        float* Hprev = Q + qElems;
        float* Dsum  = Hprev + qElems;
        ssm_pass1<<<dim3(NC, NEG, BATCH), EDG, 0, stream>>>(x, dl, A, B, Q, Dsum);
        ssm_pass2<<<(BATCH * ED * NS) / 256, 256, 0, stream>>>(A, Q, Dsum, Hprev);
        ssm_pass3<<<dim3(NC, NEG, BATCH), EDG, 0, stream>>>(x, dl, A, B, C, Dv, Hprev, y);
    } else {
        ssm_fallback<<<dim3(NEG, BATCH), EDG, 0, stream>>>(x, dl, A, B, C, Dv, y);
    }
}